// Round 12
// baseline (220.181 us; speedup 1.0000x reference)
//
#include <hip/hip_runtime.h>
#include <hip/hip_bf16.h>

#define S_LEN 1024
#define DM 256
#define NTOK 32768

typedef __attribute__((ext_vector_type(8))) short short8;
typedef __attribute__((ext_vector_type(4))) short s16x4;
typedef __attribute__((ext_vector_type(4))) float f32x4;

__device__ __forceinline__ float bf2f(unsigned short u) {
    return __uint_as_float(((unsigned int)u) << 16);
}
__device__ __forceinline__ unsigned short f2bf(float f) {
    unsigned int x = __float_as_uint(f);
    return (unsigned short)((x + 0x7fffu + ((x >> 16) & 1u)) >> 16);  // RNE
}
__device__ __forceinline__ void async16(const void* g, void* l) {
    __builtin_amdgcn_global_load_lds(
        (const __attribute__((address_space(1))) void*)g,
        (__attribute__((address_space(3))) void*)l, 16, 0, 0);
}
__device__ __forceinline__ float fast_rcp(float x) {
    float r;
    asm volatile("v_rcp_f32 %0, %1" : "=v"(r) : "v"(x));
    return r;
}

// ---- bf16 weight convert (1 MB/dir x 2 layers) -------------------------
__global__ void convert_w_kernel(const float* __restrict__ WF,
                                 const float* __restrict__ WB,
                                 short* __restrict__ WbF,
                                 short* __restrict__ WbB) {
    int dir = blockIdx.y;
    const float* src = dir ? WB : WF;
    short* dst = dir ? WbB : WbF;
    int idx = blockIdx.x * blockDim.x + threadIdx.x;  // 65536 threads x 8
    const float4* p = (const float4*)src + (size_t)idx * 2;
    float4 a = p[0], b = p[1];
    short8 v;
    v[0] = (short)f2bf(a.x); v[1] = (short)f2bf(a.y);
    v[2] = (short)f2bf(a.z); v[3] = (short)f2bf(a.w);
    v[4] = (short)f2bf(b.x); v[5] = (short)f2bf(b.y);
    v[6] = (short)f2bf(b.z); v[7] = (short)f2bf(b.w);
    ((short8*)dst)[idx] = v;
}

// ---- stage one 16KB W half-slice: pass-rows (256) x K=32 ----------------
// Ws block layout: slot s = eg*64 + lc*4 + kq, 16B each. eg<8: nl row-group
// (pass*128 + eg*16 + lc); eg>=8: gate (+256). k = h*32 + kq*8.
// w-frag read = contiguous 1KB per eg -> bank-conflict-free.
// LDS dest = wave-uniform base (HW adds lane*16).
__device__ __forceinline__ void stage_w16(const short* __restrict__ Wsub, int pass, int h,
                                          short* Wbuf, int wv, int l) {
#pragma unroll
    for (int r = 0; r < 2; r++) {
        int s0 = r * 512 + wv * 64;      // wave-uniform slot base
        int s = s0 + l;
        int eg = s >> 6;
        int lc2 = (s >> 2) & 15;
        int kq = s & 3;
        int row = ((eg & 8) << 5) + pass * 128 + (eg & 7) * 16 + lc2;
        const short* g = Wsub + (size_t)row * DM + h * 32 + kq * 8;
        async16((const void*)g, (void*)(Wbuf + (size_t)s0 * 8));
    }
}

// ---- fused per-layer kernel ---------------------------------------------
// grid (512, 2): 64-token tiles x direction. 512 threads (8 waves).
// Per sub-layer: 2 N-passes (acc[4][2]=32 AGPR, spill-free), K pipelined
// through double-buffered 16KB Ws with counted vmcnt. Swapped-operand MFMA
// (A=W, B=x) -> lane owns 4 consecutive e -> vectorized epilogue.
template <int IN_F32, int LAST>
__global__ __launch_bounds__(512, 4)
void layer_kernel(const void* xinF_, const void* xinB_,
                  const float* __restrict__ fpad, const float* __restrict__ bpad,
                  const float* __restrict__ fw5, const float* __restrict__ bw5,
                  const short* __restrict__ WF_, const short* __restrict__ WB_,
                  const float* __restrict__ bF_, const float* __restrict__ bB_,
                  short* __restrict__ xoutF, short* __restrict__ xoutB,
                  float* __restrict__ outp) {
    int dir = blockIdx.y;
    const void* xin = dir ? xinB_ : xinF_;
    const short* W = dir ? WB_ : WF_;
    const float* bias = dir ? bB_ : bF_;
    short* xout = dir ? xoutB : xoutF;
    const float* pad = dir ? bpad : fpad;
    const float* w5g = dir ? bw5 : fw5;
    int ch0 = dir ? 256 : 0;

    __shared__ __align__(16) short As[64 * DM];      // 32 KB activations
    __shared__ __align__(16) short Wst[2][1024 * 8]; // 2 x 16 KB W halves

    int tid = threadIdx.x;
    int wv = tid >> 6;
    int l = tid & 63;
    int lc = l & 15;
    int krow = l >> 4;
    int t0 = blockIdx.x * 64;

    // prologue: stage round 0 (sub0, pass0, h0) -> overlaps taps
    stage_w16(W, 0, 0, (short*)Wst[0], wv, l);

    float wj5[5];
#pragma unroll
    for (int j = 0; j < 5; j++) wj5[j] = w5g[j];

    // ---- phase 1: 5-tap conv into swizzled As ----
#pragma unroll
    for (int p = 0; p < 4; p++) {
        int pos = p * 512 + tid;
        int row = pos >> 5;
        int c = pos & 31;
        int d0 = c << 3;
        int tg = t0 + row;
        int s = tg & (S_LEN - 1);
        float a8[8];
#pragma unroll
        for (int i = 0; i < 8; i++) a8[i] = 0.0f;
#pragma unroll
        for (int j = 0; j < 5; j++) {
            float wj = wj5[j];
            bool use_pad = (dir == 0) ? (s + j < 4) : (s + j >= S_LEN);
            if (use_pad) {
                const float* pf = (dir == 0) ? (pad + (size_t)(s + j) * DM + d0)
                                             : (pad + (size_t)(s + j - S_LEN) * DM + d0);
                const float4* q = (const float4*)pf;
                float4 a = q[0], b = q[1];
                a8[0] += wj * a.x; a8[1] += wj * a.y; a8[2] += wj * a.z; a8[3] += wj * a.w;
                a8[4] += wj * b.x; a8[5] += wj * b.y; a8[6] += wj * b.z; a8[7] += wj * b.w;
            } else {
                long st = (dir == 0) ? ((long)tg + j - 4) : ((long)tg + j);
                if (IN_F32) {
                    const float4* q = (const float4*)((const float*)xin + st * DM + d0);
                    float4 a = q[0], b = q[1];
                    a8[0] += wj * a.x; a8[1] += wj * a.y; a8[2] += wj * a.z; a8[3] += wj * a.w;
                    a8[4] += wj * b.x; a8[5] += wj * b.y; a8[6] += wj * b.z; a8[7] += wj * b.w;
                } else {
                    short8 v = *(const short8*)((const short*)xin + st * DM + d0);
#pragma unroll
                    for (int i = 0; i < 8; i++) a8[i] += wj * bf2f((unsigned short)v[i]);
                }
            }
        }
        short8 o;
#pragma unroll
        for (int i = 0; i < 8; i++) o[i] = (short)f2bf(a8[i]);
        *(short8*)(As + row * DM + ((c ^ (row & 7)) << 3)) = o;
    }
    // As-ready barrier folded into round 0's top barrier.

    s16x4 ysave[2][4];
    f32x4 zero = {0.f, 0.f, 0.f, 0.f};

#pragma unroll 1
    for (int sub = 0; sub < 2; sub++) {
        const float* bsub = bias + sub * 512;
#pragma unroll
        for (int pass = 0; pass < 2; pass++) {
            f32x4 acc[4][2];
#pragma unroll
            for (int i = 0; i < 4; i++) { acc[i][0] = zero; acc[i][1] = zero; }

#pragma unroll 1
            for (int h = 0; h < 8; h++) {
                int r = sub * 16 + pass * 8 + h;
                const short* curW = (const short*)Wst[r & 1];
                if (r < 31) {
                    int rn = r + 1;
                    stage_w16(W + (size_t)(rn >> 4) * 512 * DM, (rn >> 3) & 1, rn & 7,
                              (short*)Wst[rn & 1], wv, l);
                    asm volatile("s_waitcnt vmcnt(2)" ::: "memory");  // round r staged
                } else {
                    asm volatile("s_waitcnt vmcnt(0)" ::: "memory");
                }
                __syncthreads();   // curW ready; (h==0: As/y writes visible)

                short8 w0 = *(const short8*)(curW + (wv * 64 + lc * 4 + krow) * 8);
                short8 w1 = *(const short8*)(curW + ((8 + wv) * 64 + lc * 4 + krow) * 8);
                int c = h * 4 + krow;
#pragma unroll
                for (int mf = 0; mf < 4; mf++) {
                    int row = mf * 16 + lc;
                    short8 a = *(const short8*)(As + row * DM + ((c ^ (row & 7)) << 3));
                    acc[mf][0] = __builtin_amdgcn_mfma_f32_16x16x32_bf16(w0, a, acc[mf][0], 0, 0, 0);
                    acc[mf][1] = __builtin_amdgcn_mfma_f32_16x16x32_bf16(w1, a, acc[mf][1], 0, 0, 0);
                }
                __syncthreads();   // reads done before next round stages over curW's pair
            }

            // ---- pass epilogue -> y registers (C: row=e, col=token) ----
            {
                int e0 = pass * 128 + wv * 16 + krow * 4;
                f32x4 bn = *(const f32x4*)(bsub + e0);
                f32x4 bg = *(const f32x4*)(bsub + 256 + e0);
#pragma unroll
                for (int mf = 0; mf < 4; mf++) {
                    int t = mf * 16 + lc;
                    int sx = t * DM + (((e0 >> 3) ^ (t & 7)) << 3) + (e0 & 7);
                    s16x4 xv = *(const s16x4*)(As + sx);
                    s16x4 yv;
#pragma unroll
                    for (int r = 0; r < 4; r++) {
                        float xe = bf2f((unsigned short)xv[r]);
                        float nlv = acc[mf][0][r] + bn[r];
                        float gv = acc[mf][1][r] + bg[r];
                        float g = fast_rcp(1.0f + __expf(-gv));
                        float y = g * xe + (1.0f - g) * fmaxf(nlv, 0.0f);
                        yv[r] = (short)f2bf(y);
                    }
                    ysave[pass][mf] = yv;
                }
            }
        }
        __syncthreads();   // all epilogue x-reads of As complete
        // ---- write y back to As (in place) ----
#pragma unroll
        for (int pass = 0; pass < 2; pass++) {
            int e0 = pass * 128 + wv * 16 + krow * 4;
#pragma unroll
            for (int mf = 0; mf < 4; mf++) {
                int t = mf * 16 + lc;
                int sx = t * DM + (((e0 >> 3) ^ (t & 7)) << 3) + (e0 & 7);
                *(s16x4*)(As + sx) = ysave[pass][mf];
            }
        }
        __syncthreads();   // y visible for next sub-layer / writeout
    }

    // ---- phase 4: coalesced writeout from As ----
#pragma unroll
    for (int it = 0; it < 8; it++) {
        int pos = it * 512 + tid;            // 4096 float4 positions
        int row = pos >> 6;
        int c4 = (pos & 63) << 2;
        int sx = row * DM + (((c4 >> 3) ^ (row & 7)) << 3) + (c4 & 7);
        s16x4 v = *(const s16x4*)(As + sx);
        float4 o;
        o.x = bf2f((unsigned short)v[0]);
        o.y = bf2f((unsigned short)v[1]);
        o.z = bf2f((unsigned short)v[2]);
        o.w = bf2f((unsigned short)v[3]);
        *(float4*)(outp + (size_t)(t0 + row) * 512 + ch0 + c4) = o;
    }
    if (!LAST) {
#pragma unroll
        for (int it = 0; it < 4; it++) {
            int pos = it * 512 + tid;        // 2048 short8 positions
            int row = pos >> 5;
            int c8 = (pos & 31) << 3;
            int sx = row * DM + (((c8 >> 3) ^ (row & 7)) << 3);
            short8 v = *(const short8*)(As + sx);
            *(short8*)(xout + (size_t)(t0 + row) * DM + c8) = v;
        }
    }
}

extern "C" void kernel_launch(void* const* d_in, const int* in_sizes, int n_in,
                              void* d_out, int out_size, void* d_ws, size_t ws_size,
                              hipStream_t stream) {
    const float* inputs = (const float*)d_in[0];
    const float* fwd_pad = (const float*)d_in[1];
    const float* bwd_pad = (const float*)d_in[2];
    const float* fwd_w = (const float*)d_in[3];
    const float* bwd_w = (const float*)d_in[4];
    const float* fwd_hw_W = (const float*)d_in[5];
    const float* fwd_hw_b = (const float*)d_in[6];
    const float* bwd_hw_W = (const float*)d_in[7];
    const float* bwd_hw_b = (const float*)d_in[8];
    float* out = (float*)d_out;

    const size_t XN = (size_t)NTOK * DM;          // 8,388,608 bf16 per state buf
    const size_t WN = (size_t)2 * 2 * 512 * 256;  // per-dir bf16 weight elems
    short* curF = (short*)d_ws;
    short* curB = curF + XN;
    short* WbF = curB + XN;
    short* WbB = WbF + WN;  // total ws: 32 MB state + 4 MB weights

    convert_w_kernel<<<dim3(256, 2), dim3(256), 0, stream>>>(fwd_hw_W, bwd_hw_W, WbF, WbB);

    // layer 0: reads fp32 inputs (both dirs), writes bf16 state + fp32 out
    layer_kernel<1, 0><<<dim3(512, 2), dim3(512), 0, stream>>>(
        (const void*)inputs, (const void*)inputs,
        fwd_pad, bwd_pad, fwd_w, bwd_w,
        WbF, WbB, fwd_hw_b, bwd_hw_b,
        curF, curB, out);

    // layer 1: reads bf16 state, writes fp32 out only
    layer_kernel<0, 1><<<dim3(512, 2), dim3(512), 0, stream>>>(
        (const void*)curF, (const void*)curB,
        fwd_pad + 4 * DM, bwd_pad + 4 * DM, fwd_w + 5, bwd_w + 5,
        WbF + 2 * 512 * DM, WbB + 2 * 512 * DM,
        fwd_hw_b + 1024, bwd_hw_b + 1024,
        nullptr, nullptr, out + (size_t)NTOK * 512);
}

// Round 13
// 182.622 us; speedup vs baseline: 1.2057x; 1.2057x over previous
//
#include <hip/hip_runtime.h>
#include <hip/hip_bf16.h>

#define S_LEN 1024
#define DM 256
#define NTOK 32768
#define W_SLICE 16384   // shorts per 32KB K-slice (2048 slots x 8)
#define W_SUB   131072  // shorts per sub-layer GEMM (8 slices)
#define W_LAYER 262144  // shorts per layer (2 sub-layers)

typedef __attribute__((ext_vector_type(8))) short short8;
typedef __attribute__((ext_vector_type(4))) short s16x4;
typedef __attribute__((ext_vector_type(4))) float f32x4;

__device__ __forceinline__ float bf2f(unsigned short u) {
    return __uint_as_float(((unsigned int)u) << 16);
}
__device__ __forceinline__ unsigned short f2bf(float f) {
    unsigned int x = __float_as_uint(f);
    return (unsigned short)((x + 0x7fffu + ((x >> 16) & 1u)) >> 16);  // RNE
}
__device__ __forceinline__ void async16(const void* g, void* l) {
    __builtin_amdgcn_global_load_lds(
        (const __attribute__((address_space(1))) void*)g,
        (__attribute__((address_space(3))) void*)l, 16, 0, 0);
}
__device__ __forceinline__ float fast_rcp(float x) {
    float r;
    asm volatile("v_rcp_f32 %0, %1" : "=v"(r) : "v"(x));
    return r;
}

// ---- W convert + pre-fragmentation --------------------------------------
// Output layout per (layer,sub) chunk of 131072 shorts:
//   slice ks (16384 shorts) -> slot s (0..2047, 16B each):
//   s = (wv*4 + f)*64 + l ; holds W[e][k0..k0+8] with
//   e = (f>>1)*256 + wv*32 + (f&1)*16 + (l&15), k0 = ks*32 + (l>>4)*8.
// So in-kernel staging is a LINEAR copy and each wave's 4 w-frag
// ds_read_b128 are lane-contiguous 1KB blocks (conflict-free).
__global__ void convert_w_kernel(const float* __restrict__ WF,
                                 const float* __restrict__ WB,
                                 short* __restrict__ WbF,
                                 short* __restrict__ WbB) {
    int dirv = blockIdx.y;
    const float* src = dirv ? WB : WF;
    short* dst = dirv ? WbB : WbF;
    int idx = blockIdx.x * blockDim.x + threadIdx.x;  // 65536 slots
    int chunk = idx >> 14;          // layer*2+sub
    int within = idx & 16383;
    int ks = within >> 11;
    int slot = within & 2047;
    int wvf = slot >> 6;
    int l = slot & 63;
    int wv = wvf >> 2;
    int f = wvf & 3;
    int lc = l & 15;
    int krow = l >> 4;
    int e = ((f >> 1) << 8) + wv * 32 + ((f & 1) << 4) + lc;
    int k0 = ks * 32 + krow * 8;
    const float* p = src + (size_t)chunk * W_SUB + (size_t)e * DM + k0;
    float4 a = *(const float4*)p;
    float4 b = *(const float4*)(p + 4);
    short8 v;
    v[0] = (short)f2bf(a.x); v[1] = (short)f2bf(a.y);
    v[2] = (short)f2bf(a.z); v[3] = (short)f2bf(a.w);
    v[4] = (short)f2bf(b.x); v[5] = (short)f2bf(b.y);
    v[6] = (short)f2bf(b.z); v[7] = (short)f2bf(b.w);
    *(short8*)(dst + (size_t)chunk * W_SUB + (size_t)ks * W_SLICE + (size_t)slot * 8) = v;
}

// ---- linear stage of one 32KB pre-fragmented K-slice --------------------
__device__ __forceinline__ void stage_w(const short* __restrict__ slice, short* Ws, int tid) {
    int wvb = tid & 448;  // wv*64
#pragma unroll
    for (int r = 0; r < 4; r++) {
        async16((const void*)(slice + (size_t)(r * 512 + tid) * 8),
                (void*)(Ws + (size_t)(r * 512 + wvb) * 8));
    }
}

// ---- fused per-layer kernel: taps -> hw1 -> hw2 -> writeout -------------
// grid (512, 2): 64-token tiles x direction. 512 threads (8 waves).
// LDS: As 32KB (in-place through all phases) + Ws 32KB (W K-slice) = 64KB.
// Swapped-operand MFMA (A=W-frag, B=x-frag): C row=e, col=token ->
// lane owns 4 consecutive e -> vectorized in-place epilogue.
template <int IN_F32, int LAST>
__global__ __launch_bounds__(512, 4)
void layer_kernel(const void* xinF_, const void* xinB_,
                  const float* __restrict__ fpad, const float* __restrict__ bpad,
                  const float* __restrict__ fw5, const float* __restrict__ bw5,
                  const short* __restrict__ WF_, const short* __restrict__ WB_,
                  const float* __restrict__ bF_, const float* __restrict__ bB_,
                  short* __restrict__ xoutF, short* __restrict__ xoutB,
                  float* __restrict__ outp) {
    int dir = blockIdx.y;
    const void* xin = dir ? xinB_ : xinF_;
    const short* Wlay = dir ? WB_ : WF_;
    const float* bias = dir ? bB_ : bF_;
    short* xout = dir ? xoutB : xoutF;
    const float* pad = dir ? bpad : fpad;
    const float* w5g = dir ? bw5 : fw5;
    int ch0 = dir ? 256 : 0;

    __shared__ __align__(16) short As[64 * DM];   // 32 KB
    __shared__ __align__(16) short Ws[2048 * 8];  // 32 KB

    int tid = threadIdx.x;
    int wv = tid >> 6;
    int l = tid & 63;
    int lc = l & 15;
    int krow = l >> 4;
    int t0 = blockIdx.x * 64;

    // prologue: stage sub0 slice0 (overlaps taps)
    stage_w(Wlay, Ws, tid);

    float wj5[5];
#pragma unroll
    for (int j = 0; j < 5; j++) wj5[j] = w5g[j];

    // ---- phase 1: 5-tap conv into swizzled As ----
#pragma unroll
    for (int p = 0; p < 4; p++) {
        int pos = p * 512 + tid;
        int row = pos >> 5;
        int c = pos & 31;
        int d0 = c << 3;
        int tg = t0 + row;
        int s = tg & (S_LEN - 1);
        float a8[8];
#pragma unroll
        for (int i = 0; i < 8; i++) a8[i] = 0.0f;
#pragma unroll
        for (int j = 0; j < 5; j++) {
            float wj = wj5[j];
            bool use_pad = (dir == 0) ? (s + j < 4) : (s + j >= S_LEN);
            if (use_pad) {
                const float* pf = (dir == 0) ? (pad + (size_t)(s + j) * DM + d0)
                                             : (pad + (size_t)(s + j - S_LEN) * DM + d0);
                const float4* q = (const float4*)pf;
                float4 a = q[0], b = q[1];
                a8[0] += wj * a.x; a8[1] += wj * a.y; a8[2] += wj * a.z; a8[3] += wj * a.w;
                a8[4] += wj * b.x; a8[5] += wj * b.y; a8[6] += wj * b.z; a8[7] += wj * b.w;
            } else {
                long st = (dir == 0) ? ((long)tg + j - 4) : ((long)tg + j);
                if (IN_F32) {
                    const float4* q = (const float4*)((const float*)xin + st * DM + d0);
                    float4 a = q[0], b = q[1];
                    a8[0] += wj * a.x; a8[1] += wj * a.y; a8[2] += wj * a.z; a8[3] += wj * a.w;
                    a8[4] += wj * b.x; a8[5] += wj * b.y; a8[6] += wj * b.z; a8[7] += wj * b.w;
                } else {
                    short8 v = *(const short8*)((const short*)xin + st * DM + d0);
#pragma unroll
                    for (int i = 0; i < 8; i++) a8[i] += wj * bf2f((unsigned short)v[i]);
                }
            }
        }
        short8 o;
#pragma unroll
        for (int i = 0; i < 8; i++) o[i] = (short)f2bf(a8[i]);
        *(short8*)(As + row * DM + ((c ^ (row & 7)) << 3)) = o;
    }

    f32x4 zero = {0.f, 0.f, 0.f, 0.f};

#pragma unroll 1
    for (int sub = 0; sub < 2; sub++) {
        const short* Wsub = Wlay + (size_t)sub * W_SUB;
        f32x4 acc[4][4];
#pragma unroll
        for (int i = 0; i < 4; i++)
#pragma unroll
            for (int j = 0; j < 4; j++) acc[i][j] = zero;

#pragma unroll 1
        for (int ks = 0; ks < 8; ks++) {
            asm volatile("s_waitcnt vmcnt(0)" ::: "memory");
            __syncthreads();   // slice ks ready (and As/y writes visible on ks==0)

            const short* wbase = Ws + wv * 2048;
            short8 w0 = *(const short8*)(wbase + l * 8);          // e = wv*32+lc
            short8 w1 = *(const short8*)(wbase + 512 + l * 8);    // e = wv*32+16+lc
            short8 w2 = *(const short8*)(wbase + 1024 + l * 8);   // gate e
            short8 w3 = *(const short8*)(wbase + 1536 + l * 8);
            int k8 = ks * 4 + krow;
#pragma unroll
            for (int mf = 0; mf < 4; mf++) {
                int row = mf * 16 + lc;
                short8 a = *(const short8*)(As + row * DM + ((k8 ^ (row & 7)) << 3));
                acc[mf][0] = __builtin_amdgcn_mfma_f32_16x16x32_bf16(w0, a, acc[mf][0], 0, 0, 0);
                acc[mf][1] = __builtin_amdgcn_mfma_f32_16x16x32_bf16(w1, a, acc[mf][1], 0, 0, 0);
                acc[mf][2] = __builtin_amdgcn_mfma_f32_16x16x32_bf16(w2, a, acc[mf][2], 0, 0, 0);
                acc[mf][3] = __builtin_amdgcn_mfma_f32_16x16x32_bf16(w3, a, acc[mf][3], 0, 0, 0);
            }
            __syncthreads();   // all Ws/As reads done
            if (ks < 7) stage_w(Wsub + (size_t)(ks + 1) * W_SLICE, Ws, tid);
            else if (sub == 0) stage_w(Wlay + W_SUB, Ws, tid);  // sub1 slice0
        }

        // ---- epilogue: in-register, in-place on As (owner-lane slots) ----
        const float* bsub = bias + sub * 512;
#pragma unroll
        for (int np = 0; np < 2; np++) {
            int e0 = wv * 32 + np * 16 + krow * 4;
            f32x4 bn = *(const f32x4*)(bsub + e0);
            f32x4 bg = *(const f32x4*)(bsub + 256 + e0);
#pragma unroll
            for (int mf = 0; mf < 4; mf++) {
                int t = mf * 16 + lc;
                int sx = t * DM + (((e0 >> 3) ^ (t & 7)) << 3) + (e0 & 7);
                s16x4 xv = *(const s16x4*)(As + sx);
                s16x4 yv;
#pragma unroll
                for (int r = 0; r < 4; r++) {
                    float xe = bf2f((unsigned short)xv[r]);
                    float nlv = acc[mf][np][r] + bn[r];
                    float gv = acc[mf][np + 2][r] + bg[r];
                    float g = fast_rcp(1.0f + __expf(-gv));
                    float rl = fmaxf(nlv, 0.0f);
                    float y = __builtin_fmaf(g, xe - rl, rl);  // g*x + (1-g)*relu
                    yv[r] = (short)f2bf(y);
                }
                *(s16x4*)(As + sx) = yv;
            }
        }
    }
    __syncthreads();   // y visible to all lanes for writeout

    // ---- phase 4: coalesced writeout from As ----
#pragma unroll
    for (int it = 0; it < 8; it++) {
        int pos = it * 512 + tid;            // 4096 float4 positions
        int row = pos >> 6;
        int c4 = (pos & 63) << 2;
        int sx = row * DM + (((c4 >> 3) ^ (row & 7)) << 3) + (c4 & 7);
        s16x4 v = *(const s16x4*)(As + sx);
        float4 o;
        o.x = bf2f((unsigned short)v[0]);
        o.y = bf2f((unsigned short)v[1]);
        o.z = bf2f((unsigned short)v[2]);
        o.w = bf2f((unsigned short)v[3]);
        *(float4*)(outp + (size_t)(t0 + row) * 512 + ch0 + c4) = o;
    }
    if (!LAST) {
#pragma unroll
        for (int it = 0; it < 4; it++) {
            int pos = it * 512 + tid;        // 2048 short8 positions
            int row = pos >> 5;
            int c8 = (pos & 31) << 3;
            int sx = row * DM + (((c8 >> 3) ^ (row & 7)) << 3);
            short8 v = *(const short8*)(As + sx);
            *(short8*)(xout + (size_t)(t0 + row) * DM + c8) = v;
        }
    }
}

extern "C" void kernel_launch(void* const* d_in, const int* in_sizes, int n_in,
                              void* d_out, int out_size, void* d_ws, size_t ws_size,
                              hipStream_t stream) {
    const float* inputs = (const float*)d_in[0];
    const float* fwd_pad = (const float*)d_in[1];
    const float* bwd_pad = (const float*)d_in[2];
    const float* fwd_w = (const float*)d_in[3];
    const float* bwd_w = (const float*)d_in[4];
    const float* fwd_hw_W = (const float*)d_in[5];
    const float* fwd_hw_b = (const float*)d_in[6];
    const float* bwd_hw_W = (const float*)d_in[7];
    const float* bwd_hw_b = (const float*)d_in[8];
    float* out = (float*)d_out;

    const size_t XN = (size_t)NTOK * DM;  // 8,388,608 bf16 per state buf
    const size_t WN = (size_t)2 * W_LAYER;
    short* curF = (short*)d_ws;
    short* curB = curF + XN;
    short* WbF = curB + XN;
    short* WbB = WbF + WN;  // total ws: 32 MB state + 4 MB weights

    convert_w_kernel<<<dim3(256, 2), dim3(256), 0, stream>>>(fwd_hw_W, bwd_hw_W, WbF, WbB);

    // layer 0: reads fp32 inputs (both dirs), writes bf16 state + fp32 out
    layer_kernel<1, 0><<<dim3(512, 2), dim3(512), 0, stream>>>(
        (const void*)inputs, (const void*)inputs,
        fwd_pad, bwd_pad, fwd_w, bwd_w,
        WbF, WbB, fwd_hw_b, bwd_hw_b,
        curF, curB, out);

    // layer 1: reads bf16 state, writes fp32 out only
    layer_kernel<0, 1><<<dim3(512, 2), dim3(512), 0, stream>>>(
        (const void*)curF, (const void*)curB,
        fwd_pad + 4 * DM, bwd_pad + 4 * DM, fwd_w + 5, bwd_w + 5,
        WbF + W_LAYER, WbB + W_LAYER,
        fwd_hw_b + 1024, bwd_hw_b + 1024,
        nullptr, nullptr, out + (size_t)NTOK * 512);
}

// Round 14
// 167.684 us; speedup vs baseline: 1.3131x; 1.0891x over previous
//
#include <hip/hip_runtime.h>
#include <hip/hip_bf16.h>

#define S_LEN 1024
#define DM 256
#define NTOK 32768
#define W_SLICE 16384   // shorts per K-slice (2048 slots x 8)
#define W_SUB   131072  // shorts per sub-layer GEMM (8 slices)
#define W_LAYER 262144  // shorts per layer (2 sub-layers)

typedef __attribute__((ext_vector_type(8))) short short8;
typedef __attribute__((ext_vector_type(4))) short s16x4;
typedef __attribute__((ext_vector_type(4))) float f32x4;

__device__ __forceinline__ float bf2f(unsigned short u) {
    return __uint_as_float(((unsigned int)u) << 16);
}
__device__ __forceinline__ unsigned short f2bf(float f) {
    unsigned int x = __float_as_uint(f);
    return (unsigned short)((x + 0x7fffu + ((x >> 16) & 1u)) >> 16);  // RNE
}
__device__ __forceinline__ float fast_rcp(float x) {
    float r;
    asm volatile("v_rcp_f32 %0, %1" : "=v"(r) : "v"(x));
    return r;
}

// ---- W convert + pre-fragmentation --------------------------------------
// Per (layer,sub) chunk of 131072 shorts, slice ks (16384 shorts),
// slot s = (wv*4 + f)*64 + l (16B each):
//   holds W[e][k0..k0+8], e = (f>>1)*256 + wv*32 + (f&1)*16 + (l&15),
//   k0 = ks*32 + (l>>4)*8.
// -> in-kernel fragment read = lane-contiguous 1KB global load per wave.
__global__ void convert_w_kernel(const float* __restrict__ WF,
                                 const float* __restrict__ WB,
                                 short* __restrict__ WbF,
                                 short* __restrict__ WbB) {
    int dirv = blockIdx.y;
    const float* src = dirv ? WB : WF;
    short* dst = dirv ? WbB : WbF;
    int idx = blockIdx.x * blockDim.x + threadIdx.x;  // 65536 slots
    int chunk = idx >> 14;          // layer*2+sub
    int within = idx & 16383;
    int ks = within >> 11;
    int slot = within & 2047;
    int wvf = slot >> 6;
    int l = slot & 63;
    int wv = wvf >> 2;
    int f = wvf & 3;
    int lc = l & 15;
    int krow = l >> 4;
    int e = ((f >> 1) << 8) + wv * 32 + ((f & 1) << 4) + lc;
    int k0 = ks * 32 + krow * 8;
    const float* p = src + (size_t)chunk * W_SUB + (size_t)e * DM + k0;
    float4 a = *(const float4*)p;
    float4 b = *(const float4*)(p + 4);
    short8 v;
    v[0] = (short)f2bf(a.x); v[1] = (short)f2bf(a.y);
    v[2] = (short)f2bf(a.z); v[3] = (short)f2bf(a.w);
    v[4] = (short)f2bf(b.x); v[5] = (short)f2bf(b.y);
    v[6] = (short)f2bf(b.z); v[7] = (short)f2bf(b.w);
    *(short8*)(dst + (size_t)chunk * W_SUB + (size_t)ks * W_SLICE + (size_t)slot * 8) = v;
}

// ---- fused per-layer kernel: taps -> hw1 -> hw2 -> writeout -------------
// grid (512, 2): 64-token tiles x direction. 512 threads (8 waves).
// LDS: As 32KB only. W-frags read straight from L2 (pre-fragged, coalesced
// 1KB/wave-instr) into registers -> NO K-loop barriers, waves free-run.
// Swapped-operand MFMA (A=W-frag, B=x-frag): C row=e, col=token ->
// lane owns 4 consecutive e -> vectorized in-place epilogue on As.
template <int IN_F32, int LAST>
__global__ __launch_bounds__(512, 4)
void layer_kernel(const void* xinF_, const void* xinB_,
                  const float* __restrict__ fpad, const float* __restrict__ bpad,
                  const float* __restrict__ fw5, const float* __restrict__ bw5,
                  const short* __restrict__ WF_, const short* __restrict__ WB_,
                  const float* __restrict__ bF_, const float* __restrict__ bB_,
                  short* __restrict__ xoutF, short* __restrict__ xoutB,
                  float* __restrict__ outp) {
    int dir = blockIdx.y;
    const void* xin = dir ? xinB_ : xinF_;
    const short* Wlay = dir ? WB_ : WF_;
    const float* bias = dir ? bB_ : bF_;
    short* xout = dir ? xoutB : xoutF;
    const float* pad = dir ? bpad : fpad;
    const float* w5g = dir ? bw5 : fw5;
    int ch0 = dir ? 256 : 0;

    __shared__ __align__(16) short As[64 * DM];   // 32 KB

    int tid = threadIdx.x;
    int wv = tid >> 6;
    int l = tid & 63;
    int lc = l & 15;
    int krow = l >> 4;
    int t0 = blockIdx.x * 64;

    float wj5[5];
#pragma unroll
    for (int j = 0; j < 5; j++) wj5[j] = w5g[j];

    // ---- phase 1: 5-tap conv into swizzled As ----
#pragma unroll
    for (int p = 0; p < 4; p++) {
        int pos = p * 512 + tid;
        int row = pos >> 5;
        int c = pos & 31;
        int d0 = c << 3;
        int tg = t0 + row;
        int s = tg & (S_LEN - 1);
        float a8[8];
#pragma unroll
        for (int i = 0; i < 8; i++) a8[i] = 0.0f;
#pragma unroll
        for (int j = 0; j < 5; j++) {
            float wj = wj5[j];
            bool use_pad = (dir == 0) ? (s + j < 4) : (s + j >= S_LEN);
            if (use_pad) {
                const float* pf = (dir == 0) ? (pad + (size_t)(s + j) * DM + d0)
                                             : (pad + (size_t)(s + j - S_LEN) * DM + d0);
                const float4* q = (const float4*)pf;
                float4 a = q[0], b = q[1];
                a8[0] += wj * a.x; a8[1] += wj * a.y; a8[2] += wj * a.z; a8[3] += wj * a.w;
                a8[4] += wj * b.x; a8[5] += wj * b.y; a8[6] += wj * b.z; a8[7] += wj * b.w;
            } else {
                long st = (dir == 0) ? ((long)tg + j - 4) : ((long)tg + j);
                if (IN_F32) {
                    const float4* q = (const float4*)((const float*)xin + st * DM + d0);
                    float4 a = q[0], b = q[1];
                    a8[0] += wj * a.x; a8[1] += wj * a.y; a8[2] += wj * a.z; a8[3] += wj * a.w;
                    a8[4] += wj * b.x; a8[5] += wj * b.y; a8[6] += wj * b.z; a8[7] += wj * b.w;
                } else {
                    short8 v = *(const short8*)((const short*)xin + st * DM + d0);
#pragma unroll
                    for (int i = 0; i < 8; i++) a8[i] += wj * bf2f((unsigned short)v[i]);
                }
            }
        }
        short8 o;
#pragma unroll
        for (int i = 0; i < 8; i++) o[i] = (short)f2bf(a8[i]);
        *(short8*)(As + row * DM + ((c ^ (row & 7)) << 3)) = o;
    }
    __syncthreads();   // As ready

    f32x4 zero = {0.f, 0.f, 0.f, 0.f};

#pragma unroll 1
    for (int sub = 0; sub < 2; sub++) {
        // per-wave fragment base: slot (wv*4+f)*64 + l -> shorts offset
        const short* wp = Wlay + (size_t)sub * W_SUB + (size_t)wv * 2048 + (size_t)l * 8;

        f32x4 acc[4][4];
#pragma unroll
        for (int i = 0; i < 4; i++)
#pragma unroll
            for (int j = 0; j < 4; j++) acc[i][j] = zero;

#pragma unroll 2
        for (int ks = 0; ks < 8; ks++) {
            const short* wk = wp + (size_t)ks * W_SLICE;
            short8 w0 = *(const short8*)(wk);
            short8 w1 = *(const short8*)(wk + 512);
            short8 w2 = *(const short8*)(wk + 1024);
            short8 w3 = *(const short8*)(wk + 1536);
            int k8 = ks * 4 + krow;
#pragma unroll
            for (int mf = 0; mf < 4; mf++) {
                int row = mf * 16 + lc;
                short8 a = *(const short8*)(As + row * DM + ((k8 ^ (row & 7)) << 3));
                acc[mf][0] = __builtin_amdgcn_mfma_f32_16x16x32_bf16(w0, a, acc[mf][0], 0, 0, 0);
                acc[mf][1] = __builtin_amdgcn_mfma_f32_16x16x32_bf16(w1, a, acc[mf][1], 0, 0, 0);
                acc[mf][2] = __builtin_amdgcn_mfma_f32_16x16x32_bf16(w2, a, acc[mf][2], 0, 0, 0);
                acc[mf][3] = __builtin_amdgcn_mfma_f32_16x16x32_bf16(w3, a, acc[mf][3], 0, 0, 0);
            }
        }
        __syncthreads();   // all waves' As reads done before in-place writes

        // ---- epilogue: in-register, in-place on As (owner-lane slots) ----
        const float* bsub = bias + sub * 512;
#pragma unroll
        for (int np = 0; np < 2; np++) {
            int e0 = wv * 32 + np * 16 + krow * 4;
            f32x4 bn = *(const f32x4*)(bsub + e0);
            f32x4 bg = *(const f32x4*)(bsub + 256 + e0);
#pragma unroll
            for (int mf = 0; mf < 4; mf++) {
                int t = mf * 16 + lc;
                int sx = t * DM + (((e0 >> 3) ^ (t & 7)) << 3) + (e0 & 7);
                s16x4 xv = *(const s16x4*)(As + sx);
                s16x4 yv;
#pragma unroll
                for (int r = 0; r < 4; r++) {
                    float xe = bf2f((unsigned short)xv[r]);
                    float nlv = acc[mf][np][r] + bn[r];
                    float gv = acc[mf][np + 2][r] + bg[r];
                    float g = fast_rcp(1.0f + __expf(-gv));
                    float rl = fmaxf(nlv, 0.0f);
                    float y = __builtin_fmaf(g, xe - rl, rl);  // g*x + (1-g)*relu
                    yv[r] = (short)f2bf(y);
                }
                *(s16x4*)(As + sx) = yv;
            }
        }
        __syncthreads();   // y visible before next sub-layer reads / writeout
    }

    // ---- phase 4: coalesced writeout from As ----
#pragma unroll
    for (int it = 0; it < 8; it++) {
        int pos = it * 512 + tid;            // 4096 float4 positions
        int row = pos >> 6;
        int c4 = (pos & 63) << 2;
        int sx = row * DM + (((c4 >> 3) ^ (row & 7)) << 3) + (c4 & 7);
        s16x4 v = *(const s16x4*)(As + sx);
        float4 o;
        o.x = bf2f((unsigned short)v[0]);
        o.y = bf2f((unsigned short)v[1]);
        o.z = bf2f((unsigned short)v[2]);
        o.w = bf2f((unsigned short)v[3]);
        *(float4*)(outp + (size_t)(t0 + row) * 512 + ch0 + c4) = o;
    }
    if (!LAST) {
#pragma unroll
        for (int it = 0; it < 4; it++) {
            int pos = it * 512 + tid;        // 2048 short8 positions
            int row = pos >> 5;
            int c8 = (pos & 31) << 3;
            int sx = row * DM + (((c8 >> 3) ^ (row & 7)) << 3);
            short8 v = *(const short8*)(As + sx);
            *(short8*)(xout + (size_t)(t0 + row) * DM + c8) = v;
        }
    }
}

extern "C" void kernel_launch(void* const* d_in, const int* in_sizes, int n_in,
                              void* d_out, int out_size, void* d_ws, size_t ws_size,
                              hipStream_t stream) {
    const float* inputs = (const float*)d_in[0];
    const float* fwd_pad = (const float*)d_in[1];
    const float* bwd_pad = (const float*)d_in[2];
    const float* fwd_w = (const float*)d_in[3];
    const float* bwd_w = (const float*)d_in[4];
    const float* fwd_hw_W = (const float*)d_in[5];
    const float* fwd_hw_b = (const float*)d_in[6];
    const float* bwd_hw_W = (const float*)d_in[7];
    const float* bwd_hw_b = (const float*)d_in[8];
    float* out = (float*)d_out;

    const size_t XN = (size_t)NTOK * DM;  // 8,388,608 bf16 per state buf
    const size_t WN = (size_t)2 * W_LAYER;
    short* curF = (short*)d_ws;
    short* curB = curF + XN;
    short* WbF = curB + XN;
    short* WbB = WbF + WN;  // total ws: 32 MB state + 4 MB weights

    convert_w_kernel<<<dim3(256, 2), dim3(256), 0, stream>>>(fwd_hw_W, bwd_hw_W, WbF, WbB);

    // layer 0: reads fp32 inputs (both dirs), writes bf16 state + fp32 out
    layer_kernel<1, 0><<<dim3(512, 2), dim3(512), 0, stream>>>(
        (const void*)inputs, (const void*)inputs,
        fwd_pad, bwd_pad, fwd_w, bwd_w,
        WbF, WbB, fwd_hw_b, bwd_hw_b,
        curF, curB, out);

    // layer 1: reads bf16 state, writes fp32 out only
    layer_kernel<0, 1><<<dim3(512, 2), dim3(512), 0, stream>>>(
        (const void*)curF, (const void*)curB,
        fwd_pad + 4 * DM, bwd_pad + 4 * DM, fwd_w + 5, bwd_w + 5,
        WbF + W_LAYER, WbB + W_LAYER,
        fwd_hw_b + 1024, bwd_hw_b + 1024,
        nullptr, nullptr, out + (size_t)NTOK * 512);
}

// Round 15
// 126.091 us; speedup vs baseline: 1.7462x; 1.3299x over previous
//
#include <hip/hip_runtime.h>
#include <hip/hip_bf16.h>

#define S_LEN 1024
#define DM 256
#define NTOK 32768
#define OWN 56          // owned output rows per block (64-row tile, 4-row halo/side)
#define NBLK 586        // ceil(32768/56)
#define W_SLICE 16384   // shorts per K-slice (2048 slots x 8)
#define W_SUB   131072  // shorts per sub-layer GEMM
#define W_LAYER 262144  // shorts per layer

typedef __attribute__((ext_vector_type(8))) short short8;
typedef __attribute__((ext_vector_type(4))) short s16x4;
typedef __attribute__((ext_vector_type(4))) float f32x4;

__device__ __forceinline__ float bf2f(unsigned short u) {
    return __uint_as_float(((unsigned int)u) << 16);
}
__device__ __forceinline__ unsigned short f2bf(float f) {
    unsigned int x = __float_as_uint(f);
    return (unsigned short)((x + 0x7fffu + ((x >> 16) & 1u)) >> 16);  // RNE
}
__device__ __forceinline__ float fast_rcp(float x) {
    float r;
    asm volatile("v_rcp_f32 %0, %1" : "=v"(r) : "v"(x));
    return r;
}

// ---- W convert + pre-fragmentation (unchanged from r13/r14) -------------
// Per (layer,sub) chunk of 131072 shorts, slice ks, slot s = (wv*4+f)*64+l:
//   W[e][k0..k0+8], e = (f>>1)*256 + wv*32 + (f&1)*16 + (l&15),
//   k0 = ks*32 + (l>>4)*8.  Fragment read = lane-contiguous 1KB per wave.
__global__ void convert_w_kernel(const float* __restrict__ WF,
                                 const float* __restrict__ WB,
                                 short* __restrict__ WbF,
                                 short* __restrict__ WbB) {
    int dirv = blockIdx.y;
    const float* src = dirv ? WB : WF;
    short* dst = dirv ? WbB : WbF;
    int idx = blockIdx.x * blockDim.x + threadIdx.x;  // 65536 slots
    int chunk = idx >> 14;          // layer*2+sub
    int within = idx & 16383;
    int ks = within >> 11;
    int slot = within & 2047;
    int wvf = slot >> 6;
    int l = slot & 63;
    int wv = wvf >> 2;
    int f = wvf & 3;
    int lc = l & 15;
    int krow = l >> 4;
    int e = ((f >> 1) << 8) + wv * 32 + ((f & 1) << 4) + lc;
    int k0 = ks * 32 + krow * 8;
    const float* p = src + (size_t)chunk * W_SUB + (size_t)e * DM + k0;
    float4 a = *(const float4*)p;
    float4 b = *(const float4*)(p + 4);
    short8 v;
    v[0] = (short)f2bf(a.x); v[1] = (short)f2bf(a.y);
    v[2] = (short)f2bf(a.z); v[3] = (short)f2bf(a.w);
    v[4] = (short)f2bf(b.x); v[5] = (short)f2bf(b.y);
    v[6] = (short)f2bf(b.z); v[7] = (short)f2bf(b.w);
    *(short8*)(dst + (size_t)chunk * W_SUB + (size_t)ks * W_SLICE + (size_t)slot * 8) = v;
}

// ---- one highway sub-layer on a 64-row LDS tile (r14 core) --------------
// GEMM: W-frags straight from L2 (pre-fragged, 1KB coalesced), A from
// swizzled LDS; no K-loop barriers. Swapped-operand MFMA -> lane owns 4
// consecutive e -> vectorized in-place epilogue.
__device__ __forceinline__ void hw_sub(short* Xs, const short* __restrict__ Wsub,
                                       const float* __restrict__ bsub,
                                       int wv, int l, int lc, int krow) {
    f32x4 zero = {0.f, 0.f, 0.f, 0.f};
    f32x4 acc[4][4];
#pragma unroll
    for (int i = 0; i < 4; i++)
#pragma unroll
        for (int j = 0; j < 4; j++) acc[i][j] = zero;

    const short* wp = Wsub + (size_t)wv * 2048 + (size_t)l * 8;
#pragma unroll 2
    for (int ks = 0; ks < 8; ks++) {
        const short* wk = wp + (size_t)ks * W_SLICE;
        short8 w0 = *(const short8*)(wk);
        short8 w1 = *(const short8*)(wk + 512);
        short8 w2 = *(const short8*)(wk + 1024);
        short8 w3 = *(const short8*)(wk + 1536);
        int k8 = ks * 4 + krow;
#pragma unroll
        for (int mf = 0; mf < 4; mf++) {
            int row = mf * 16 + lc;
            short8 a = *(const short8*)(Xs + row * DM + ((k8 ^ (row & 7)) << 3));
            acc[mf][0] = __builtin_amdgcn_mfma_f32_16x16x32_bf16(w0, a, acc[mf][0], 0, 0, 0);
            acc[mf][1] = __builtin_amdgcn_mfma_f32_16x16x32_bf16(w1, a, acc[mf][1], 0, 0, 0);
            acc[mf][2] = __builtin_amdgcn_mfma_f32_16x16x32_bf16(w2, a, acc[mf][2], 0, 0, 0);
            acc[mf][3] = __builtin_amdgcn_mfma_f32_16x16x32_bf16(w3, a, acc[mf][3], 0, 0, 0);
        }
    }
    __syncthreads();   // all As reads done before in-place writes

    const float* bsub2 = bsub + 256;
#pragma unroll
    for (int np = 0; np < 2; np++) {
        int e0 = wv * 32 + np * 16 + krow * 4;
        f32x4 bn = *(const f32x4*)(bsub + e0);
        f32x4 bg = *(const f32x4*)(bsub2 + e0);
#pragma unroll
        for (int mf = 0; mf < 4; mf++) {
            int t = mf * 16 + lc;
            int sx = t * DM + (((e0 >> 3) ^ (t & 7)) << 3) + (e0 & 7);
            s16x4 xv = *(const s16x4*)(Xs + sx);
            s16x4 yv;
#pragma unroll
            for (int r = 0; r < 4; r++) {
                float xe = bf2f((unsigned short)xv[r]);
                float nlv = acc[mf][np][r] + bn[r];
                float gv = acc[mf][np + 2][r] + bg[r];
                float g = fast_rcp(1.0f + __expf(-gv));
                float rl = fmaxf(nlv, 0.0f);
                float y = __builtin_fmaf(g, xe - rl, rl);  // g*x + (1-g)*relu
                yv[r] = (short)f2bf(y);
            }
            *(s16x4*)(Xs + sx) = yv;
        }
    }
    __syncthreads();   // y visible for next phase
}

// ---- fully fused BiLM: taps0 -> hw0a -> hw0b -> taps1(LDS) -> hw1a ->
//      hw1b -> writeout. grid (586, 2). 512 threads (8 waves).
// Block owns output rows [t0, t0+56); LDS tile covers rows t0-4..t0+59.
__global__ __launch_bounds__(512, 4)
void bilm_kernel(const float* __restrict__ xin,
                 const float* __restrict__ fpad, const float* __restrict__ bpad,
                 const float* __restrict__ fw5, const float* __restrict__ bw5,
                 const short* __restrict__ WbF, const short* __restrict__ WbB,
                 const float* __restrict__ bF_, const float* __restrict__ bB_,
                 float* __restrict__ outp) {
    int dir = blockIdx.y;
    const short* Wd = dir ? WbB : WbF;
    const float* biasd = dir ? bB_ : bF_;
    const float* padd = dir ? bpad : fpad;
    const float* w5d = dir ? bw5 : fw5;
    int ch0 = dir ? 256 : 0;

    __shared__ __align__(16) short As[64 * DM];   // layer-0 tile (swizzled)
    __shared__ __align__(16) short Bs[64 * DM];   // layer-1 tile

    int tid = threadIdx.x;
    int wv = tid >> 6;
    int l = tid & 63;
    int lc = l & 15;
    int krow = l >> 4;
    int t0 = blockIdx.x * OWN;
    int base = t0 - 4;   // lrow 0 <-> token base

    // ---- phase A: layer-0 taps from global fp32 x -> As (64 rows) ----
    {
        float wj5[5];
#pragma unroll
        for (int j = 0; j < 5; j++) wj5[j] = w5d[j];
#pragma unroll
        for (int p = 0; p < 4; p++) {
            int pos = p * 512 + tid;
            int row = pos >> 5;
            int c = pos & 31;
            int d0 = c << 3;
            int tg = base + row;
            int s = tg & (S_LEN - 1);
            float a8[8];
#pragma unroll
            for (int i = 0; i < 8; i++) a8[i] = 0.0f;
#pragma unroll
            for (int j = 0; j < 5; j++) {
                float wj = wj5[j];
                bool use_pad = (dir == 0) ? (s + j < 4) : (s + j >= S_LEN);
                if (use_pad) {
                    const float* pf = (dir == 0) ? (padd + (size_t)(s + j) * DM + d0)
                                                 : (padd + (size_t)(s + j - S_LEN) * DM + d0);
                    const float4* q = (const float4*)pf;
                    float4 a = q[0], b = q[1];
                    a8[0] += wj * a.x; a8[1] += wj * a.y; a8[2] += wj * a.z; a8[3] += wj * a.w;
                    a8[4] += wj * b.x; a8[5] += wj * b.y; a8[6] += wj * b.z; a8[7] += wj * b.w;
                } else {
                    long st = (dir == 0) ? ((long)tg + j - 4) : ((long)tg + j);
                    st = st < 0 ? 0 : (st >= NTOK ? NTOK - 1 : st);  // halo clamp
                    const float4* q = (const float4*)(xin + st * DM + d0);
                    float4 a = q[0], b = q[1];
                    a8[0] += wj * a.x; a8[1] += wj * a.y; a8[2] += wj * a.z; a8[3] += wj * a.w;
                    a8[4] += wj * b.x; a8[5] += wj * b.y; a8[6] += wj * b.z; a8[7] += wj * b.w;
                }
            }
            short8 o;
#pragma unroll
            for (int i = 0; i < 8; i++) o[i] = (short)f2bf(a8[i]);
            *(short8*)(As + row * DM + ((c ^ (row & 7)) << 3)) = o;
        }
    }
    __syncthreads();

    // ---- phase B: layer-0 highway (in place on As) ----
    hw_sub(As, Wd, biasd, wv, l, lc, krow);
    hw_sub(As, Wd + W_SUB, biasd + 512, wv, l, lc, krow);

    // ---- phase C: layer-1 taps from As -> Bs ----
    {
        float wj5[5];
#pragma unroll
        for (int j = 0; j < 5; j++) wj5[j] = w5d[5 + j];
        const float* padl1 = padd + 4 * DM;
#pragma unroll
        for (int p = 0; p < 4; p++) {
            int pos = p * 512 + tid;
            int row = pos >> 5;
            int c = pos & 31;
            int d0 = c << 3;
            int tg = base + row;
            int s = tg & (S_LEN - 1);
            float a8[8];
#pragma unroll
            for (int i = 0; i < 8; i++) a8[i] = 0.0f;
#pragma unroll
            for (int j = 0; j < 5; j++) {
                float wj = wj5[j];
                bool use_pad = (dir == 0) ? (s + j < 4) : (s + j >= S_LEN);
                if (use_pad) {
                    const float* pf = (dir == 0) ? (padl1 + (size_t)(s + j) * DM + d0)
                                                 : (padl1 + (size_t)(s + j - S_LEN) * DM + d0);
                    const float4* q = (const float4*)pf;
                    float4 a = q[0], b = q[1];
                    a8[0] += wj * a.x; a8[1] += wj * a.y; a8[2] += wj * a.z; a8[3] += wj * a.w;
                    a8[4] += wj * b.x; a8[5] += wj * b.y; a8[6] += wj * b.z; a8[7] += wj * b.w;
                } else {
                    int srow = (dir == 0) ? (row + j - 4) : (row + j);
                    srow = srow < 0 ? 0 : (srow > 63 ? 63 : srow);  // halo clamp
                    short8 v = *(const short8*)(As + srow * DM + ((c ^ (srow & 7)) << 3));
#pragma unroll
                    for (int i = 0; i < 8; i++) a8[i] += wj * bf2f((unsigned short)v[i]);
                }
            }
            short8 o;
#pragma unroll
            for (int i = 0; i < 8; i++) o[i] = (short)f2bf(a8[i]);
            *(short8*)(Bs + row * DM + ((c ^ (row & 7)) << 3)) = o;
        }
    }
    __syncthreads();

    // ---- phase D: layer-1 highway (in place on Bs) ----
    hw_sub(Bs, Wd + W_LAYER, biasd + 1024, wv, l, lc, krow);
    hw_sub(Bs, Wd + W_LAYER + W_SUB, biasd + 1536, wv, l, lc, krow);

    // ---- phase E: coalesced writeout of owned rows (lrow 4..59) ----
#pragma unroll
    for (int it = 0; it < 7; it++) {
        int pos = it * 512 + tid;        // 3584 float4 positions (56 rows x 64)
        int row = pos >> 6;
        int c4 = (pos & 63) << 2;
        int t = t0 + row;
        if (t < NTOK) {
            int lr = row + 4;
            int sx = lr * DM + (((c4 >> 3) ^ (lr & 7)) << 3) + (c4 & 7);
            s16x4 v0 = *(const s16x4*)(As + sx);
            s16x4 v1 = *(const s16x4*)(Bs + sx);
            float4 o0, o1;
            o0.x = bf2f((unsigned short)v0[0]); o0.y = bf2f((unsigned short)v0[1]);
            o0.z = bf2f((unsigned short)v0[2]); o0.w = bf2f((unsigned short)v0[3]);
            o1.x = bf2f((unsigned short)v1[0]); o1.y = bf2f((unsigned short)v1[1]);
            o1.z = bf2f((unsigned short)v1[2]); o1.w = bf2f((unsigned short)v1[3]);
            *(float4*)(outp + (size_t)t * 512 + ch0 + c4) = o0;
            *(float4*)(outp + (size_t)NTOK * 512 + (size_t)t * 512 + ch0 + c4) = o1;
        }
    }
}

extern "C" void kernel_launch(void* const* d_in, const int* in_sizes, int n_in,
                              void* d_out, int out_size, void* d_ws, size_t ws_size,
                              hipStream_t stream) {
    const float* inputs = (const float*)d_in[0];
    const float* fwd_pad = (const float*)d_in[1];
    const float* bwd_pad = (const float*)d_in[2];
    const float* fwd_w = (const float*)d_in[3];
    const float* bwd_w = (const float*)d_in[4];
    const float* fwd_hw_W = (const float*)d_in[5];
    const float* fwd_hw_b = (const float*)d_in[6];
    const float* bwd_hw_W = (const float*)d_in[7];
    const float* bwd_hw_b = (const float*)d_in[8];
    float* out = (float*)d_out;

    short* WbF = (short*)d_ws;
    short* WbB = WbF + (size_t)2 * W_LAYER;  // 2 MB total

    convert_w_kernel<<<dim3(256, 2), dim3(256), 0, stream>>>(fwd_hw_W, bwd_hw_W, WbF, WbB);

    bilm_kernel<<<dim3(NBLK, 2), dim3(512), 0, stream>>>(
        inputs, fwd_pad, bwd_pad, fwd_w, bwd_w,
        WbF, WbB, fwd_hw_b, bwd_hw_b, out);
}

// Round 17
// 121.083 us; speedup vs baseline: 1.8184x; 1.0414x over previous
//
#include <hip/hip_runtime.h>
#include <hip/hip_bf16.h>

#define S_LEN 1024
#define DM 256
#define NTOK 32768
#define OWN 56          // owned output rows per block (64-row tile, 4-row halo/side)
#define NBLK 586        // ceil(32768/56)
#define W_SLICE 16384   // shorts per K-slice (2048 slots x 8)
#define W_SUB   131072  // shorts per sub-layer GEMM
#define W_LAYER 262144  // shorts per layer

typedef __attribute__((ext_vector_type(8))) short short8;
typedef __attribute__((ext_vector_type(4))) short s16x4;
typedef __attribute__((ext_vector_type(4))) float f32x4;

__device__ __forceinline__ float bf2f(unsigned short u) {
    return __uint_as_float(((unsigned int)u) << 16);
}
__device__ __forceinline__ short f2bf(float f) {
    __hip_bfloat16 h = __float2bfloat16(f);   // HW RNE convert (1 op, pair-fusable)
    return *reinterpret_cast<short*>(&h);
}
__device__ __forceinline__ float sigmoid_fast(float x) {
    // 1/(1+exp(-x)) = rcp(1 + exp2(-log2(e)*x)); raw HW trans ops
    float e = __builtin_amdgcn_exp2f(x * -1.442695041f);
    return __builtin_amdgcn_rcpf(1.0f + e);
}

// ---- W convert + pre-fragmentation (layout unchanged from r13/r14) ------
// Per (layer,sub) chunk of 131072 shorts, slice ks, slot s = (wv*4+f)*64+l:
//   W[e][k0..k0+8], e = (f>>1)*256 + wv*32 + (f&1)*16 + (l&15),
//   k0 = ks*32 + (l>>4)*8.  Fragment read = lane-contiguous 1KB per wave.
__global__ void convert_w_kernel(const float* __restrict__ WF,
                                 const float* __restrict__ WB,
                                 short* __restrict__ WbF,
                                 short* __restrict__ WbB) {
    int dirv = blockIdx.y;
    const float* src = dirv ? WB : WF;
    short* dst = dirv ? WbB : WbF;
    int idx = blockIdx.x * blockDim.x + threadIdx.x;  // 65536 slots
    int chunk = idx >> 14;          // layer*2+sub
    int within = idx & 16383;
    int ks = within >> 11;
    int slot = within & 2047;
    int wvf = slot >> 6;
    int l = slot & 63;
    int wv = wvf >> 2;
    int f = wvf & 3;
    int lc = l & 15;
    int krow = l >> 4;
    int e = ((f >> 1) << 8) + wv * 32 + ((f & 1) << 4) + lc;
    int k0 = ks * 32 + krow * 8;
    const float* p = src + (size_t)chunk * W_SUB + (size_t)e * DM + k0;
    float4 a = *(const float4*)p;
    float4 b = *(const float4*)(p + 4);
    short8 v;
    v[0] = f2bf(a.x); v[1] = f2bf(a.y); v[2] = f2bf(a.z); v[3] = f2bf(a.w);
    v[4] = f2bf(b.x); v[5] = f2bf(b.y); v[6] = f2bf(b.z); v[7] = f2bf(b.w);
    *(short8*)(dst + (size_t)chunk * W_SUB + (size_t)ks * W_SLICE + (size_t)slot * 8) = v;
}

// ---- one highway sub-layer on a 64-row LDS tile (r14 core) --------------
__device__ __forceinline__ void hw_sub(short* Xs, const short* __restrict__ Wsub,
                                       const float* __restrict__ bsub,
                                       int wv, int l, int lc, int krow) {
    f32x4 zero = {0.f, 0.f, 0.f, 0.f};
    f32x4 acc[4][4];
#pragma unroll
    for (int i = 0; i < 4; i++)
#pragma unroll
        for (int j = 0; j < 4; j++) acc[i][j] = zero;

    const short* wp = Wsub + (size_t)wv * 2048 + (size_t)l * 8;
    __builtin_amdgcn_s_setprio(1);
#pragma unroll 2
    for (int ks = 0; ks < 8; ks++) {
        const short* wk = wp + (size_t)ks * W_SLICE;
        short8 w0 = *(const short8*)(wk);
        short8 w1 = *(const short8*)(wk + 512);
        short8 w2 = *(const short8*)(wk + 1024);
        short8 w3 = *(const short8*)(wk + 1536);
        int k8 = ks * 4 + krow;
#pragma unroll
        for (int mf = 0; mf < 4; mf++) {
            int row = mf * 16 + lc;
            short8 a = *(const short8*)(Xs + row * DM + ((k8 ^ (row & 7)) << 3));
            acc[mf][0] = __builtin_amdgcn_mfma_f32_16x16x32_bf16(w0, a, acc[mf][0], 0, 0, 0);
            acc[mf][1] = __builtin_amdgcn_mfma_f32_16x16x32_bf16(w1, a, acc[mf][1], 0, 0, 0);
            acc[mf][2] = __builtin_amdgcn_mfma_f32_16x16x32_bf16(w2, a, acc[mf][2], 0, 0, 0);
            acc[mf][3] = __builtin_amdgcn_mfma_f32_16x16x32_bf16(w3, a, acc[mf][3], 0, 0, 0);
        }
    }
    __builtin_amdgcn_s_setprio(0);
    __syncthreads();   // all As reads done before in-place writes

    const float* bsub2 = bsub + 256;
#pragma unroll
    for (int np = 0; np < 2; np++) {
        int e0 = wv * 32 + np * 16 + krow * 4;
        f32x4 bn = *(const f32x4*)(bsub + e0);
        f32x4 bg = *(const f32x4*)(bsub2 + e0);
#pragma unroll
        for (int mf = 0; mf < 4; mf++) {
            int t = mf * 16 + lc;
            int sx = t * DM + (((e0 >> 3) ^ (t & 7)) << 3) + (e0 & 7);
            s16x4 xv = *(const s16x4*)(Xs + sx);
            s16x4 yv;
#pragma unroll
            for (int r = 0; r < 4; r++) {
                float xe = bf2f((unsigned short)xv[r]);
                float nlv = acc[mf][np][r] + bn[r];
                float gv = acc[mf][np + 2][r] + bg[r];
                float g = sigmoid_fast(gv);
                float rl = fmaxf(nlv, 0.0f);
                float y = __builtin_fmaf(g, xe - rl, rl);  // g*x + (1-g)*relu
                yv[r] = f2bf(y);
            }
            *(s16x4*)(Xs + sx) = yv;
        }
    }
    __syncthreads();   // y visible for next phase
}

// ---- fully fused BiLM: taps0 -> hw0a -> hw0b -> taps1(LDS) -> hw1a ->
//      hw1b -> writeout. grid (586, 2). 512 threads (8 waves).
__global__ __launch_bounds__(512, 4)
void bilm_kernel(const float* __restrict__ xin,
                 const float* __restrict__ fpad, const float* __restrict__ bpad,
                 const float* __restrict__ fw5, const float* __restrict__ bw5,
                 const short* __restrict__ WbF, const short* __restrict__ WbB,
                 const float* __restrict__ bF_, const float* __restrict__ bB_,
                 float* __restrict__ outp) {
    int dir = blockIdx.y;
    const short* Wd = dir ? WbB : WbF;
    const float* biasd = dir ? bB_ : bF_;
    const float* padd = dir ? bpad : fpad;
    const float* w5d = dir ? bw5 : fw5;
    int ch0 = dir ? 256 : 0;

    __shared__ __align__(16) short As[64 * DM];   // layer-0 tile (swizzled)
    __shared__ __align__(16) short Bs[64 * DM];   // layer-1 tile

    int tid = threadIdx.x;
    int wv = tid >> 6;
    int l = tid & 63;
    int lc = l & 15;
    int krow = l >> 4;
    int t0 = blockIdx.x * OWN;
    int base = t0 - 4;   // lrow 0 <-> token base

    // ---- phase A: layer-0 taps from global fp32 x -> As (64 rows) ----
    {
        float wj5[5];
#pragma unroll
        for (int j = 0; j < 5; j++) wj5[j] = w5d[j];
#pragma unroll
        for (int p = 0; p < 4; p++) {
            int pos = p * 512 + tid;
            int row = pos >> 5;
            int c = pos & 31;
            int d0 = c << 3;
            int tg = base + row;
            int s = tg & (S_LEN - 1);
            float a8[8];
#pragma unroll
            for (int i = 0; i < 8; i++) a8[i] = 0.0f;
#pragma unroll
            for (int j = 0; j < 5; j++) {
                float wj = wj5[j];
                bool use_pad = (dir == 0) ? (s + j < 4) : (s + j >= S_LEN);
                if (use_pad) {
                    const float* pf = (dir == 0) ? (padd + (size_t)(s + j) * DM + d0)
                                                 : (padd + (size_t)(s + j - S_LEN) * DM + d0);
                    const float4* q = (const float4*)pf;
                    float4 a = q[0], b = q[1];
                    a8[0] += wj * a.x; a8[1] += wj * a.y; a8[2] += wj * a.z; a8[3] += wj * a.w;
                    a8[4] += wj * b.x; a8[5] += wj * b.y; a8[6] += wj * b.z; a8[7] += wj * b.w;
                } else {
                    long st = (dir == 0) ? ((long)tg + j - 4) : ((long)tg + j);
                    st = st < 0 ? 0 : (st >= NTOK ? NTOK - 1 : st);  // halo clamp
                    const float4* q = (const float4*)(xin + st * DM + d0);
                    float4 a = q[0], b = q[1];
                    a8[0] += wj * a.x; a8[1] += wj * a.y; a8[2] += wj * a.z; a8[3] += wj * a.w;
                    a8[4] += wj * b.x; a8[5] += wj * b.y; a8[6] += wj * b.z; a8[7] += wj * b.w;
                }
            }
            short8 o;
#pragma unroll
            for (int i = 0; i < 8; i++) o[i] = f2bf(a8[i]);
            *(short8*)(As + row * DM + ((c ^ (row & 7)) << 3)) = o;
        }
    }
    __syncthreads();

    // ---- phase B: layer-0 highway (in place on As) ----
    hw_sub(As, Wd, biasd, wv, l, lc, krow);
    hw_sub(As, Wd + W_SUB, biasd + 512, wv, l, lc, krow);

    // ---- phase C: layer-1 taps from As -> Bs ----
    {
        float wj5[5];
#pragma unroll
        for (int j = 0; j < 5; j++) wj5[j] = w5d[5 + j];
        const float* padl1 = padd + 4 * DM;
#pragma unroll
        for (int p = 0; p < 4; p++) {
            int pos = p * 512 + tid;
            int row = pos >> 5;
            int c = pos & 31;
            int d0 = c << 3;
            int tg = base + row;
            int s = tg & (S_LEN - 1);
            float a8[8];
#pragma unroll
            for (int i = 0; i < 8; i++) a8[i] = 0.0f;
#pragma unroll
            for (int j = 0; j < 5; j++) {
                float wj = wj5[j];
                bool use_pad = (dir == 0) ? (s + j < 4) : (s + j >= S_LEN);
                if (use_pad) {
                    const float* pf = (dir == 0) ? (padl1 + (size_t)(s + j) * DM + d0)
                                                 : (padl1 + (size_t)(s + j - S_LEN) * DM + d0);
                    const float4* q = (const float4*)pf;
                    float4 a = q[0], b = q[1];
                    a8[0] += wj * a.x; a8[1] += wj * a.y; a8[2] += wj * a.z; a8[3] += wj * a.w;
                    a8[4] += wj * b.x; a8[5] += wj * b.y; a8[6] += wj * b.z; a8[7] += wj * b.w;
                } else {
                    int srow = (dir == 0) ? (row + j - 4) : (row + j);
                    srow = srow < 0 ? 0 : (srow > 63 ? 63 : srow);  // halo clamp
                    short8 v = *(const short8*)(As + srow * DM + ((c ^ (srow & 7)) << 3));
#pragma unroll
                    for (int i = 0; i < 8; i++) a8[i] += wj * bf2f((unsigned short)v[i]);
                }
            }
            short8 o;
#pragma unroll
            for (int i = 0; i < 8; i++) o[i] = f2bf(a8[i]);
            *(short8*)(Bs + row * DM + ((c ^ (row & 7)) << 3)) = o;
        }
    }
    __syncthreads();

    // ---- phase D: layer-1 highway (in place on Bs) ----
    hw_sub(Bs, Wd + W_LAYER, biasd + 1024, wv, l, lc, krow);
    hw_sub(Bs, Wd + W_LAYER + W_SUB, biasd + 1536, wv, l, lc, krow);

    // ---- phase E: coalesced writeout of owned rows (lrow 4..59) ----
#pragma unroll
    for (int it = 0; it < 7; it++) {
        int pos = it * 512 + tid;        // 3584 float4 positions (56 rows x 64)
        int row = pos >> 6;
        int c4 = (pos & 63) << 2;
        int t = t0 + row;
        if (t < NTOK) {
            int lr = row + 4;
            int sx = lr * DM + (((c4 >> 3) ^ (lr & 7)) << 3) + (c4 & 7);
            s16x4 v0 = *(const s16x4*)(As + sx);
            s16x4 v1 = *(const s16x4*)(Bs + sx);
            float4 o0, o1;
            o0.x = bf2f((unsigned short)v0[0]); o0.y = bf2f((unsigned short)v0[1]);
            o0.z = bf2f((unsigned short)v0[2]); o0.w = bf2f((unsigned short)v0[3]);
            o1.x = bf2f((unsigned short)v1[0]); o1.y = bf2f((unsigned short)v1[1]);
            o1.z = bf2f((unsigned short)v1[2]); o1.w = bf2f((unsigned short)v1[3]);
            *(float4*)(outp + (size_t)t * 512 + ch0 + c4) = o0;
            *(float4*)(outp + (size_t)NTOK * 512 + (size_t)t * 512 + ch0 + c4) = o1;
        }
    }
}

extern "C" void kernel_launch(void* const* d_in, const int* in_sizes, int n_in,
                              void* d_out, int out_size, void* d_ws, size_t ws_size,
                              hipStream_t stream) {
    const float* inputs = (const float*)d_in[0];
    const float* fwd_pad = (const float*)d_in[1];
    const float* bwd_pad = (const float*)d_in[2];
    const float* fwd_w = (const float*)d_in[3];
    const float* bwd_w = (const float*)d_in[4];
    const float* fwd_hw_W = (const float*)d_in[5];
    const float* fwd_hw_b = (const float*)d_in[6];
    const float* bwd_hw_W = (const float*)d_in[7];
    const float* bwd_hw_b = (const float*)d_in[8];
    float* out = (float*)d_out;

    short* WbF = (short*)d_ws;
    short* WbB = WbF + (size_t)2 * W_LAYER;  // 2 MB total

    convert_w_kernel<<<dim3(256, 2), dim3(256), 0, stream>>>(fwd_hw_W, bwd_hw_W, WbF, WbB);

    bilm_kernel<<<dim3(NBLK, 2), dim3(512), 0, stream>>>(
        inputs, fwd_pad, bwd_pad, fwd_w, bwd_w,
        WbF, WbB, fwd_hw_b, bwd_hw_b, out);
}